// Round 1
// baseline (57.909 us; speedup 1.0000x reference)
//
#include <hip/hip_runtime.h>
#include <cstdint>
#include <cstddef>

#define AS1 __attribute__((address_space(1)))
#define AS3 __attribute__((address_space(3)))

typedef __attribute__((ext_vector_type(8))) short bf16x8;
typedef __attribute__((ext_vector_type(4))) float f32x4;
typedef __attribute__((ext_vector_type(2))) float f32x2;
typedef __attribute__((ext_vector_type(2))) unsigned int u32x2;

static constexpr int BROWS = 262144;
static constexpr int DIM   = 64;
static constexpr int NC    = 256;
static constexpr int OUTD  = 18;
static constexpr int BM    = 128;
static constexpr int NBLK  = 256;
static constexpr int NCHUNK = BROWS / BM / NBLK;  // 8

__device__ __forceinline__ unsigned cvt_pk_bf16(float a, float b) {
  unsigned r;
  asm("v_cvt_pk_bf16_f32 %0, %1, %2" : "=v"(r) : "v"(a), "v"(b));
  return r;
}

union U4 { unsigned u[4]; bf16x8 v; };

// pack 8 f32 -> 8 bf16 (RN), order-preserving
__device__ __forceinline__ bf16x8 pack8(const float* s) {
  U4 r;
#pragma unroll
  for (int p = 0; p < 4; ++p) r.u[p] = cvt_pk_bf16(s[2*p], s[2*p+1]);
  return r.v;
}

// split 8 f32 into bf16 hi + bf16 lo (lo = RN_bf16(x - hi))
__device__ __forceinline__ void split8(const float* s, bf16x8& hi, bf16x8& lo) {
  U4 h, l;
#pragma unroll
  for (int p = 0; p < 4; ++p) {
    float a = s[2*p], b = s[2*p+1];
    unsigned ph = cvt_pk_bf16(a, b);
    float ah = __uint_as_float(ph << 16);
    float bh = __uint_as_float(ph & 0xffff0000u);
    h.u[p] = ph;
    l.u[p] = cvt_pk_bf16(a - ah, b - bh);
  }
  hi = h.v; lo = l.v;
}

__device__ __forceinline__ void gload_lds16(const void* g, void* l) {
  __builtin_amdgcn_global_load_lds((const AS1 unsigned*)g, (AS3 unsigned*)l, 16, 0, 0);
}

__global__ __launch_bounds__(256, 1) void rbf_fused(
    const float* __restrict__ x,  const float* __restrict__ Wr,
    const float* __restrict__ br, const float* __restrict__ Wl,
    const float* __restrict__ bl, float* __restrict__ out)
{
  // xs: x staged f32, source-preswizzled so linear dest + XOR-swizzled reads agree (G21).
  __shared__ __align__(16) float xs[2][BM * DIM];            // 2 x 32 KB
  __shared__ __align__(16) unsigned short feat[BM * NC];     // 64 KB (bf16 bits, XOR-swizzled 16B chunks)

  const int tid  = threadIdx.x;
  const int wav  = tid >> 6;
  const int lane = tid & 63;
  const int li   = lane & 15;
  const int g    = lane >> 4;

  const float S1 = 0.22507907903927651f;  // sqrt(2)/(2*pi): proj in revolutions
  const float SC = 0.08838834764831845f;  // sqrt(2/256)

  // ---- hoist A1 = (S1 * W_rbf)^T tile fragments, hi/lo.  nt = 4*wav + q ----
  bf16x8 a1h[4][2], a1l[4][2];
#pragma unroll
  for (int q = 0; q < 4; ++q) {
    const int n = 16 * (4*wav + q) + li;      // A1 row (component index)
#pragma unroll
    for (int kb = 0; kb < 2; ++kb) {
      float v[8];
#pragma unroll
      for (int j = 0; j < 8; ++j)
        v[j] = Wr[(size_t)(32*kb + 8*g + j) * NC + n] * S1;
      split8(v, a1h[q][kb], a1l[q][kb]);
    }
  }
  // b_rbf fragments: lane needs br[16*nt + 4g + j]
  f32x4 brf[4];
#pragma unroll
  for (int q = 0; q < 4; ++q)
    brf[q] = *(const f32x4*)(br + 16*(4*wav + q) + 4*g);

  // ---- hoist A2 = W_lin fragments (single bf16), rows o = 16t + li ----
  bf16x8 a2[2][8];
#pragma unroll
  for (int t = 0; t < 2; ++t) {
    const int o = 16*t + li;
#pragma unroll
    for (int kb = 0; kb < 8; ++kb) {
      float v[8];
      if (o < OUTD) {
        f32x4 v0 = *(const f32x4*)(Wl + o*NC + 32*kb + 8*g);
        f32x4 v1 = *(const f32x4*)(Wl + o*NC + 32*kb + 8*g + 4);
        v[0]=v0.x; v[1]=v0.y; v[2]=v0.z; v[3]=v0.w;
        v[4]=v1.x; v[5]=v1.y; v[6]=v1.z; v[7]=v1.w;
      } else {
#pragma unroll
        for (int j = 0; j < 8; ++j) v[j] = 0.f;
      }
      a2[t][kb] = pack8(v);
    }
  }
  const f32x4 bl0 = *(const f32x4*)(bl + 4*g);   // 4g+3 <= 15 < 18, safe
  const float bl16 = bl[16], bl17 = bl[17];

  const int cbase = blockIdx.x * NCHUNK;

  auto stage = [&](int chunk, int buf) {
    const float* xb = x + (size_t)chunk * BM * DIM;
#pragma unroll
    for (int c = 0; c < 8; ++c) {
      const int s  = c*4 + wav;                 // 1 KB segment = 4 rows
      const int rr = s*4 + g;                   // this lane's row
      // LDS linear slot (rr, li) receives global chunk (li ^ (rr&7))
      const float* src = xb + rr*DIM + ((li ^ (rr & 7)) << 2);
      gload_lds16(src, (void*)&xs[buf][s * 256]);
    }
  };

  stage(cbase, 0);

  for (int i = 0; i < NCHUNK; ++i) {
    const int buf = i & 1;
    if (i + 1 < NCHUNK) {
      stage(cbase + i + 1, buf ^ 1);
      asm volatile("s_waitcnt vmcnt(8)" ::: "memory");  // chunk-i stage done; i+1 stays in flight
    } else {
      asm volatile("s_waitcnt vmcnt(0)" ::: "memory");
    }
    __builtin_amdgcn_s_barrier();
    asm volatile("" ::: "memory");

    const float* xsb = &xs[buf][0];

    // ---- P1: proj^T tiles = A1(W^T) x B(x^T), 3-pass hi/lo; cos; feat -> LDS ----
#pragma unroll 2
    for (int rt = 0; rt < 8; ++rt) {
      const int rr = rt*16 + li;
      const int m  = rr & 7;
      float xv[16];
#pragma unroll
      for (int kb = 0; kb < 2; ++kb) {
        const int c0 = 8*kb + 2*g;
        f32x4 p0 = *(const f32x4*)(xsb + rr*64 + (((c0    ) ^ m) << 2));
        f32x4 p1 = *(const f32x4*)(xsb + rr*64 + (((c0 + 1) ^ m) << 2));
        xv[8*kb+0]=p0.x; xv[8*kb+1]=p0.y; xv[8*kb+2]=p0.z; xv[8*kb+3]=p0.w;
        xv[8*kb+4]=p1.x; xv[8*kb+5]=p1.y; xv[8*kb+6]=p1.z; xv[8*kb+7]=p1.w;
      }
      bf16x8 bh[2], blo_[2];
      split8(xv,     bh[0], blo_[0]);
      split8(xv + 8, bh[1], blo_[1]);

      f32x4 acc[4];
#pragma unroll
      for (int q = 0; q < 4; ++q) acc[q] = f32x4{0.f, 0.f, 0.f, 0.f};
#pragma unroll
      for (int kb = 0; kb < 2; ++kb) {
#pragma unroll
        for (int q = 0; q < 4; ++q) {
          acc[q] = __builtin_amdgcn_mfma_f32_16x16x32_bf16(a1h[q][kb], bh[kb],   acc[q], 0, 0, 0);
          acc[q] = __builtin_amdgcn_mfma_f32_16x16x32_bf16(a1l[q][kb], bh[kb],   acc[q], 0, 0, 0);
          acc[q] = __builtin_amdgcn_mfma_f32_16x16x32_bf16(a1h[q][kb], blo_[kb], acc[q], 0, 0, 0);
        }
      }
      // rev = proj(revolutions) + b_rbf; feat = cos(2*pi*rev)*SC, bf16, packed 8B write
#pragma unroll
      for (int q = 0; q < 4; ++q) {
        float c4[4];
#pragma unroll
        for (int j = 0; j < 4; ++j) {
          float rev = acc[q][j] + brf[q][j];
          float f   = rev - floorf(rev);                 // [0,1) revolutions
          c4[j] = __builtin_amdgcn_cosf(f) * SC;         // v_cos_f32 takes revolutions
        }
        u32x2 pk;
        pk.x = cvt_pk_bf16(c4[0], c4[1]);
        pk.y = cvt_pk_bf16(c4[2], c4[3]);
        const int nt   = 4*wav + q;
        const int slot = (2*nt + (g >> 1)) ^ m;          // 16B-chunk XOR swizzle
        *(u32x2*)(&feat[rr*256 + slot*8 + (g & 1)*4]) = pk;
      }
    }
    asm volatile("s_waitcnt lgkmcnt(0)" ::: "memory");
    __builtin_amdgcn_s_barrier();
    asm volatile("" ::: "memory");

    // ---- P2: out^T tiles = A2(W_lin) x B2(feat^T) ----
#pragma unroll
    for (int r2 = 0; r2 < 2; ++r2) {
      const int rr = (2*wav + r2)*16 + li;
      const int m  = rr & 7;
      f32x4 acc0 = f32x4{0.f,0.f,0.f,0.f};
      f32x4 acc1 = f32x4{0.f,0.f,0.f,0.f};
#pragma unroll
      for (int kb = 0; kb < 8; ++kb) {
        bf16x8 b2 = *(const bf16x8*)(&feat[rr*256 + (((4*kb + g) ^ m) * 8)]);
        acc0 = __builtin_amdgcn_mfma_f32_16x16x32_bf16(a2[0][kb], b2, acc0, 0, 0, 0);
        acc1 = __builtin_amdgcn_mfma_f32_16x16x32_bf16(a2[1][kb], b2, acc1, 0, 0, 0);
      }
      const size_t rg = (size_t)(cbase + i) * BM + rr;
      float* op = out + rg * OUTD;
      f32x2 s0; s0.x = acc0.x + bl0.x; s0.y = acc0.y + bl0.y;
      f32x2 s1; s1.x = acc0.z + bl0.z; s1.y = acc0.w + bl0.w;
      *(f32x2*)(op + 4*g)     = s0;   // o = 4g..4g+3 (all < 16)
      *(f32x2*)(op + 4*g + 2) = s1;
      if (g == 0) {                   // o = 16,17
        f32x2 s2; s2.x = acc1.x + bl16; s2.y = acc1.y + bl17;
        *(f32x2*)(op + 16) = s2;
      }
    }
    asm volatile("s_waitcnt lgkmcnt(0)" ::: "memory");
    __builtin_amdgcn_s_barrier();
    asm volatile("" ::: "memory");
  }
}

extern "C" void kernel_launch(void* const* d_in, const int* in_sizes, int n_in,
                              void* d_out, int out_size, void* d_ws, size_t ws_size,
                              hipStream_t stream) {
  (void)in_sizes; (void)n_in; (void)d_ws; (void)ws_size; (void)out_size;
  const float* x  = (const float*)d_in[0];
  const float* Wr = (const float*)d_in[1];
  const float* br = (const float*)d_in[2];
  const float* Wl = (const float*)d_in[3];
  const float* bl = (const float*)d_in[4];
  rbf_fused<<<NBLK, 256, 0, stream>>>(x, Wr, br, Wl, bl, (float*)d_out);
}